// Round 7
// baseline (441.133 us; speedup 1.0000x reference)
//
#include <hip/hip_runtime.h>

#define I_DIM 32
#define J_DIM 32
#define S_DIM 256
#define H_DIM 768
#define KC    32                  // f16 elems per K-chunk
#define NCH   (H_DIM / KC)        // 24 chunks
#define TILE_B 32768              // 256 rows x 128 B (h|l slots, XOR-swizzled)
#define WSQ_BYTES ((size_t)I_DIM * NCH * TILE_B)   // 24 MB
#define WSK_BYTES ((size_t)J_DIM * NCH * TILE_B)   // 24 MB

typedef _Float16 f16x8 __attribute__((ext_vector_type(8)));
typedef float    f32x16 __attribute__((ext_vector_type(16)));

static __device__ __forceinline__ unsigned short f16bits(_Float16 h) {
    union { _Float16 f; unsigned short u; } cv; cv.f = h; return cv.u;
}

// ---------------------------------------------------------------------------
// Pre-pass: one wave per row. Normalize, split fp16 hi + fp16 residual, store
// in pre-swizzled LDS tile image: row s occupies 128 B; 16B slot for k-group
// kg (hi: kg, lo: kg^4 -> addr^64), slot index XOR (s&7).
// ---------------------------------------------------------------------------
__global__ __launch_bounds__(256) void li_split_kernel(
    const float* __restrict__ qe, const float* __restrict__ ke,
    char* __restrict__ wsQ, char* __restrict__ wsK)
{
    const int lane = threadIdx.x & 63;
    const int w    = threadIdx.x >> 6;
    const int r    = blockIdx.x * 4 + w;               // 0..16383
    const bool isQ = r < I_DIM * S_DIM;
    const int row  = isQ ? r : r - I_DIM * S_DIM;
    const float* base = (isQ ? qe : ke) + (size_t)row * H_DIM;

    float4 v[3];
    v[0] = *(const float4*)(base + 4 * lane);
    v[1] = *(const float4*)(base + 4 * lane + 256);
    v[2] = *(const float4*)(base + 4 * lane + 512);
    float ss = 0.0f;
    #pragma unroll
    for (int g = 0; g < 3; ++g)
        ss += v[g].x * v[g].x + v[g].y * v[g].y + v[g].z * v[g].z + v[g].w * v[g].w;
    #pragma unroll
    for (int m = 1; m < 64; m <<= 1) ss += __shfl_xor(ss, m, 64);
    const float inv = 1.0f / fmaxf(sqrtf(ss), 1e-12f);

    const int mi  = row >> 8;
    const int s   = row & 255;
    const int r7  = s & 7;
    char* wsb = (isQ ? wsQ : wsK) + (size_t)mi * NCH * TILE_B + s * 128;

    #pragma unroll
    for (int g = 0; g < 3; ++g) {
        const int k0 = 4 * lane + 256 * g;
        const int c  = k0 >> 5;
        const int kk = k0 & 31;
        float xn[4] = {v[g].x * inv, v[g].y * inv, v[g].z * inv, v[g].w * inv};
        unsigned short hb[4], lb[4];
        #pragma unroll
        for (int e = 0; e < 4; ++e) {
            _Float16 h  = (_Float16)xn[e];
            _Float16 lo = (_Float16)(xn[e] - (float)h);
            hb[e] = f16bits(h);
            lb[e] = f16bits(lo);
        }
        char* p = wsb + (size_t)c * TILE_B + (((kk >> 3) ^ r7) << 4) + (kk & 7) * 2;
        *(uint2*)(p)        = make_uint2(hb[0] | ((unsigned)hb[1] << 16), hb[2] | ((unsigned)hb[3] << 16));
        *(uint2*)((char*)((size_t)p ^ 64)) = make_uint2(lb[0] | ((unsigned)lb[1] << 16), lb[2] | ((unsigned)lb[3] << 16));
    }
}

// ---------------------------------------------------------------------------
// Main: 1024 threads = 16 waves in a 4(row)x4(col) grid; wave owns 64x64 =
// 2x2 MFMA 32x32 tiles (acc = 64 regs -> 4 waves/SIMD, MFMA/LDS overlap).
// Double-buffered chunk staging with counted vmcnt. Softmax col-quarters
// merged via per-row (m,L,W) partials in LDS.
// ---------------------------------------------------------------------------
__global__ __launch_bounds__(1024, 4) void li_mfma_kernel(
    const char* __restrict__ wsQ, const char* __restrict__ wsK,
    const float* __restrict__ qm, const float* __restrict__ km,
    const float* __restrict__ alpha_raw, float* __restrict__ out)
{
    __shared__ __align__(16) char sQ[2][TILE_B];
    __shared__ __align__(16) char sK[2][TILE_B];
    __shared__ float kmsh[256], qmsh[256];
    __shared__ float pm[256][4], pL[256][4], pW[256][4];
    __shared__ float redA[1024], redB[1024];

    const int tid = threadIdx.x;
    const int wid = tid >> 6;
    const int l   = tid & 63;
    const int l31 = l & 31;
    const int hi  = l >> 5;
    const int wx  = wid & 3;    // col quarter
    const int wy  = wid >> 2;   // row quarter
    const int r7  = l31 & 7;

    // XCD-aware: XCD x hosts j in {4x..4x+3} -> K_j stays L2-resident
    const int bidx = blockIdx.x;
    const int x  = bidx & 7;
    const int r0 = bidx >> 3;
    const int j  = x * 4 + (r0 & 3);
    const int i  = r0 >> 2;

    if (tid < 256) {
        kmsh[tid] = km[j * 256 + tid];
        qmsh[tid] = qm[i * 256 + tid];
    }
    const float araw  = alpha_raw[0];
    const float alpha = (araw > 20.0f) ? araw : log1pf(expf(araw));
    const float nal   = -alpha;

    const char* qbase = wsQ + (size_t)i * NCH * TILE_B;
    const char* kbase = wsK + (size_t)j * NCH * TILE_B;

    f32x16 acc[2][2];
    #pragma unroll
    for (int mr = 0; mr < 2; ++mr)
        #pragma unroll
        for (int nt = 0; nt < 2; ++nt)
            #pragma unroll
            for (int z = 0; z < 16; ++z) acc[mr][nt][z] = 0.0f;

#define STAGE(buf, c)                                                                      \
    do {                                                                                   \
        const char* qt_ = qbase + (size_t)(c) * TILE_B + wid * 2048 + l * 16;              \
        const char* kt_ = kbase + (size_t)(c) * TILE_B + wid * 2048 + l * 16;              \
        char* dq_ = sQ[buf] + wid * 2048;                                                  \
        char* dk_ = sK[buf] + wid * 2048;                                                  \
        _Pragma("unroll")                                                                  \
        for (int u = 0; u < 2; ++u)                                                        \
            __builtin_amdgcn_global_load_lds(                                              \
                (const __attribute__((address_space(1))) void*)(qt_ + u * 1024),           \
                (__attribute__((address_space(3))) void*)(dq_ + u * 1024), 16, 0, 0);      \
        _Pragma("unroll")                                                                  \
        for (int u = 0; u < 2; ++u)                                                        \
            __builtin_amdgcn_global_load_lds(                                              \
                (const __attribute__((address_space(1))) void*)(kt_ + u * 1024),           \
                (__attribute__((address_space(3))) void*)(dk_ + u * 1024), 16, 0, 0);      \
    } while (0)

    STAGE(0, 0);
    asm volatile("s_waitcnt vmcnt(0)" ::: "memory");
    __builtin_amdgcn_sched_barrier(0);
    __builtin_amdgcn_s_barrier();
    __builtin_amdgcn_sched_barrier(0);

    for (int c = 0; c < NCH; ++c) {
        if (c + 1 < NCH) {
            STAGE((c + 1) & 1, c + 1);
            // wait for chunk c's 4 loads (ours); chunk c+1's 4 stay in flight
            asm volatile("s_waitcnt vmcnt(4)" ::: "memory");
        } else {
            asm volatile("s_waitcnt vmcnt(0)" ::: "memory");
        }
        __builtin_amdgcn_sched_barrier(0);
        __builtin_amdgcn_s_barrier();   // all waves' chunk-c LDS writes visible
        __builtin_amdgcn_sched_barrier(0);

        const char* bQ = sQ[c & 1];
        const char* bK = sK[c & 1];
        #pragma unroll
        for (int ks = 0; ks < 2; ++ks) {
            const int soff = ((ks * 2 + hi) ^ r7) << 4;   // hi-slot byte offset
            const int rA = wy * 64 + l31;
            const int rB = rA + 32;
            const f16x8 qhA = *(const f16x8*)(bQ + rA * 128 + soff);
            const f16x8 qlA = *(const f16x8*)(bQ + ((rA * 128 + soff) ^ 64));
            const f16x8 qhB = *(const f16x8*)(bQ + rB * 128 + soff);
            const f16x8 qlB = *(const f16x8*)(bQ + ((rB * 128 + soff) ^ 64));
            const int c0 = wx * 64 + l31;
            const int c1 = c0 + 32;
            const f16x8 kh0 = *(const f16x8*)(bK + c0 * 128 + soff);
            const f16x8 kl0 = *(const f16x8*)(bK + ((c0 * 128 + soff) ^ 64));
            const f16x8 kh1 = *(const f16x8*)(bK + c1 * 128 + soff);
            const f16x8 kl1 = *(const f16x8*)(bK + ((c1 * 128 + soff) ^ 64));

            acc[0][0] = __builtin_amdgcn_mfma_f32_32x32x16_f16(qhA, kh0, acc[0][0], 0, 0, 0);
            acc[0][1] = __builtin_amdgcn_mfma_f32_32x32x16_f16(qhA, kh1, acc[0][1], 0, 0, 0);
            acc[1][0] = __builtin_amdgcn_mfma_f32_32x32x16_f16(qhB, kh0, acc[1][0], 0, 0, 0);
            acc[1][1] = __builtin_amdgcn_mfma_f32_32x32x16_f16(qhB, kh1, acc[1][1], 0, 0, 0);

            acc[0][0] = __builtin_amdgcn_mfma_f32_32x32x16_f16(qhA, kl0, acc[0][0], 0, 0, 0);
            acc[0][1] = __builtin_amdgcn_mfma_f32_32x32x16_f16(qhA, kl1, acc[0][1], 0, 0, 0);
            acc[1][0] = __builtin_amdgcn_mfma_f32_32x32x16_f16(qhB, kl0, acc[1][0], 0, 0, 0);
            acc[1][1] = __builtin_amdgcn_mfma_f32_32x32x16_f16(qhB, kl1, acc[1][1], 0, 0, 0);

            acc[0][0] = __builtin_amdgcn_mfma_f32_32x32x16_f16(qlA, kh0, acc[0][0], 0, 0, 0);
            acc[0][1] = __builtin_amdgcn_mfma_f32_32x32x16_f16(qlA, kh1, acc[0][1], 0, 0, 0);
            acc[1][0] = __builtin_amdgcn_mfma_f32_32x32x16_f16(qlB, kh0, acc[1][0], 0, 0, 0);
            acc[1][1] = __builtin_amdgcn_mfma_f32_32x32x16_f16(qlB, kh1, acc[1][1], 0, 0, 0);
        }
        __builtin_amdgcn_sched_barrier(0);
        __builtin_amdgcn_s_barrier();   // protect buf reuse by next STAGE
        __builtin_amdgcn_sched_barrier(0);
    }
#undef STAGE

    // ---- per-wave softmax partials over its 64-col quarter ----
    #pragma unroll
    for (int mr = 0; mr < 2; ++mr) {
        #pragma unroll
        for (int z = 0; z < 16; ++z) {
            const int srow = wy * 64 + mr * 32 + hi * 4 + (z & 3) + 8 * (z >> 2);
            const float qms = qmsh[srow];
            float mv[2], cvv[2];
            float mloc = -3.0e38f;
            #pragma unroll
            for (int nt = 0; nt < 2; ++nt) {
                const int tcol = wx * 64 + nt * 32 + l31;
                const float cv = acc[mr][nt][z];
                int dd = srow - tcol; dd = dd < 0 ? -dd : dd;
                const float valid = qms * kmsh[tcol];
                const float m = cv * __expf(nal * (float)dd) * valid - (1.0f - valid) * 1e9f;
                mv[nt] = m; cvv[nt] = cv;
                mloc = fmaxf(mloc, m);
            }
            #pragma unroll
            for (int mm = 1; mm < 32; mm <<= 1)
                mloc = fmaxf(mloc, __shfl_xor(mloc, mm, 32));
            float L = 0.0f, W = 0.0f;
            #pragma unroll
            for (int nt = 0; nt < 2; ++nt) {
                const float e = __expf(mv[nt] - mloc);
                L += e;
                W += e * cvv[nt];
            }
            #pragma unroll
            for (int mm = 1; mm < 32; mm <<= 1) {
                L += __shfl_xor(L, mm, 32);
                W += __shfl_xor(W, mm, 32);
            }
            if (l31 == 0) {
                pm[srow][wx] = mloc;
                pL[srow][wx] = L;
                pW[srow][wx] = W;
            }
        }
    }
    __syncthreads();

    // ---- merge col-quarters per row, then block-reduce ----
    float contrib = 0.0f, qq = 0.0f;
    if (tid < 256) {
        float M = fmaxf(fmaxf(pm[tid][0], pm[tid][1]), fmaxf(pm[tid][2], pm[tid][3]));
        float L = 0.0f, W = 0.0f;
        #pragma unroll
        for (int q = 0; q < 4; ++q) {
            const float e = __expf(pm[tid][q] - M);
            L += pL[tid][q] * e;
            W += pW[tid][q] * e;
        }
        contrib = (W / L) * qmsh[tid];
        qq = qmsh[tid];
    }
    redA[tid] = contrib;
    redB[tid] = qq;
    __syncthreads();
    for (int off = 512; off > 0; off >>= 1) {
        if (tid < off) {
            redA[tid] += redA[tid + off];
            redB[tid] += redB[tid + off];
        }
        __syncthreads();
    }
    if (tid == 0) out[i * 32 + j] = redA[0] / fmaxf(redB[0], 1.0f);
}

// ---------------------------------------------------------------------------
extern "C" void kernel_launch(void* const* d_in, const int* in_sizes, int n_in,
                              void* d_out, int out_size, void* d_ws, size_t ws_size,
                              hipStream_t stream)
{
    const float* qe = (const float*)d_in[0];
    const float* ke = (const float*)d_in[1];
    const float* qm = (const float*)d_in[2];
    const float* km = (const float*)d_in[3];
    const float* al = (const float*)d_in[4];
    float* out = (float*)d_out;

    char* wsQ = (char*)d_ws;
    char* wsK = wsQ + WSQ_BYTES;

    hipLaunchKernelGGL(li_split_kernel, dim3((I_DIM + J_DIM) * S_DIM / 4), dim3(256),
                       0, stream, qe, ke, wsQ, wsK);
    hipLaunchKernelGGL(li_mfma_kernel, dim3(I_DIM * J_DIM), dim3(1024), 0, stream,
                       wsQ, wsK, qm, km, al, out);
}